// Round 9
// baseline (1341.895 us; speedup 1.0000x reference)
//
#include <hip/hip_runtime.h>
#include <hip/hip_bf16.h>
#include <cstdint>
#include <cstddef>

using bf16 = __hip_bfloat16;
typedef __attribute__((ext_vector_type(8))) short short8;
typedef __attribute__((ext_vector_type(4))) float f32x4;

typedef __attribute__((address_space(1))) const void as1_void;
typedef __attribute__((address_space(3))) void as3_void;

__device__ __forceinline__ f32x4 mfma16x16x32(short8 a, short8 b, f32x4 c) {
  return __builtin_amdgcn_mfma_f32_16x16x32_bf16(a, b, c, 0, 0, 0);
}

__device__ __forceinline__ void gload_lds16(const void* g, void* l) {
  __builtin_amdgcn_global_load_lds((as1_void*)g, (as3_void*)l, 16, 0, 0);
}

__device__ __forceinline__ uint32_t cvtpk(float a, float b) {
  uint32_t r;
  asm("v_cvt_pk_bf16_f32 %0, %1, %2" : "=v"(r) : "v"(a), "v"(b));
  return r;
}

__device__ __forceinline__ float gelu_f(float v) {
  const float u = 0.7978845608f * v * (1.f + 0.044715f * v * v);
  const float e = __expf(-2.f * fabsf(u));
  const float t = (1.f - e) / (1.f + e);
  return 0.5f * v * (1.f + (u < 0.f ? -t : t));
}

// ---------------- problem constants ----------------
static constexpr int MROWS = 39200;
static constexpr int MPAD  = 39296;
static constexpr int TOK2  = 32768;

// ---------------- weight transpose+cast:  in f32 [K][N] -> out bf16 [N][K] ----
__global__ __launch_bounds__(256)
void transpose_cast(const float* __restrict__ in, bf16* __restrict__ out, int K, int N) {
  __shared__ float t[32][33];
  const int tx = threadIdx.x & 31, ty = threadIdx.x >> 5;
  const int bx = blockIdx.x, by = blockIdx.y;
  const int x = bx * 32 + tx;
  for (int r = ty; r < 32; r += 8)
    t[r][tx] = in[(size_t)(by * 32 + r) * N + x];
  __syncthreads();
  const int xo = by * 32 + tx;
  for (int r = ty; r < 32; r += 8)
    out[(size_t)(bx * 32 + r) * K + xo] = __float2bfloat16(t[tx][r]);
}

// ---------------- LN1 + window partition -> bf16 [MPAD][768] ----------------
__global__ __launch_bounds__(256)
void ln1_partition(const float* __restrict__ x, const float* __restrict__ g,
                   const float* __restrict__ bb, bf16* __restrict__ out) {
  const int token = blockIdx.x * 4 + (threadIdx.x >> 6);
  const int lane = threadIdx.x & 63;
  const int win = token / 196, tok = token % 196;
  const int b_ = win / 25, wh = (win / 5) % 5, ww = win % 5;
  const int i = tok / 14, j = tok % 14;
  const int h = wh * 14 + i, w = ww * 14 + j;
  bf16* o = out + (size_t)token * 768;
  if (h >= 64 || w >= 64) {
    for (int t = 0; t < 12; ++t) o[lane + 64 * t] = __float2bfloat16(0.f);
    return;
  }
  const float* src = x + ((size_t)((b_ * 64 + h) * 64 + w)) * 768;
  float vals[12], s = 0.f, ss = 0.f;
  #pragma unroll
  for (int t = 0; t < 12; ++t) {
    float v = src[lane + 64 * t];
    vals[t] = v; s += v; ss += v * v;
  }
  #pragma unroll
  for (int d = 32; d > 0; d >>= 1) { s += __shfl_xor(s, d); ss += __shfl_xor(ss, d); }
  const float mu = s * (1.f / 768.f);
  const float var = ss * (1.f / 768.f) - mu * mu;
  const float inv = rsqrtf(var + 1e-6f);
  #pragma unroll
  for (int t = 0; t < 12; ++t) {
    const int c = lane + 64 * t;
    o[c] = __float2bfloat16((vals[t] - mu) * inv * g[c] + bb[c]);
  }
}

// ---------------- LN2 on x1 (f32, dense [32768][768]) -> bf16 ----------------
__global__ __launch_bounds__(256)
void ln2_kernel(const float* __restrict__ x1, const float* __restrict__ g,
                const float* __restrict__ bb, bf16* __restrict__ out) {
  const int token = blockIdx.x * 4 + (threadIdx.x >> 6);
  const int lane = threadIdx.x & 63;
  const float* src = x1 + (size_t)token * 768;
  bf16* o = out + (size_t)token * 768;
  float vals[12], s = 0.f, ss = 0.f;
  #pragma unroll
  for (int t = 0; t < 12; ++t) {
    float v = src[lane + 64 * t];
    vals[t] = v; s += v; ss += v * v;
  }
  #pragma unroll
  for (int d = 32; d > 0; d >>= 1) { s += __shfl_xor(s, d); ss += __shfl_xor(ss, d); }
  const float mu = s * (1.f / 768.f);
  const float var = ss * (1.f / 768.f) - mu * mu;
  const float inv = rsqrtf(var + 1e-6f);
  #pragma unroll
  for (int t = 0; t < 12; ++t) {
    const int c = lane + 64 * t;
    o[c] = __float2bfloat16((vals[t] - mu) * inv * g[c] + bb[c]);
  }
}

// ---------------- generic bf16 GEMM, 128x128 tile, BK=32, 2-phase dbuf ------
// (r6 proven structure: __syncthreads 2-phase; counted-vmcnt was neutral at 2ph)
// EPI 0: qkv -> q [head][MPAD][64], k [head][MPAD][64], V^T [head][64][MPAD]
// EPI 1: proj (A in [head][MPAD][64]) + unpartition + residual (f32)
// EPI 2: gelu -> bf16 [M][3072] (LDS-staged stores)
// EPI 3: dense residual add (f32)
template<int EPI>
__global__ __launch_bounds__(256)
void gemm_bf16(const bf16* __restrict__ A, const bf16* __restrict__ Bt,
               const float* __restrict__ bias, int K, int Mreal,
               const float* __restrict__ fin, float* __restrict__ fout,
               bf16* __restrict__ ob0, bf16* __restrict__ ob1, bf16* __restrict__ ob2) {
  __shared__ __align__(16) bf16 SMEM[16384];                 // 32 KB
  bf16* const lA0 = SMEM;
  bf16* const lA1 = SMEM + 4096;
  bf16* const lB0 = SMEM + 8192;
  bf16* const lB1 = SMEM + 12288;
  const int tid = threadIdx.x;
  const int lane = tid & 63, wv = tid >> 6;
  const int lr = lane & 15, hi = lane >> 4;
  const int wm = wv >> 1, wn = wv & 1;

  // bijective chunked XCD swizzle (m204)
  const int gx = gridDim.x;
  const int nwg = gx * gridDim.y;
  int lin = blockIdx.y * gx + blockIdx.x;
  {
    const int q8 = nwg >> 3, r8 = nwg & 7;
    const int xcd = lin & 7, pos = lin >> 3;
    lin = (xcd < r8 ? xcd * (q8 + 1) : r8 * (q8 + 1) + (xcd - r8) * q8) + pos;
  }
  const size_t arow0 = (size_t)(lin / gx) * 128;
  const size_t brow0 = (size_t)(lin % gx) * 128;
  f32x4 acc[4][4] = {};

  auto stage = [&](bf16* bufA, bf16* bufB, int kt) {
    const int k0 = kt * 32;
    #pragma unroll
    for (int it = 0; it < 2; ++it) {
      const int seg = it * 256 + tid;
      const int row = seg >> 2, kq = seg & 3;
      const size_t dst = (size_t)(it * 256 + wv * 64) * 8;
      if constexpr (EPI == 1) {
        const int k = k0 + kq * 8;   // A layout: [head][MPAD][64]
        gload_lds16(A + ((size_t)(k >> 6) * MPAD + arow0 + row) * 64 + (k & 63), bufA + dst);
      } else {
        gload_lds16(A + (arow0 + row) * K + k0 + kq * 8, bufA + dst);
      }
      gload_lds16(Bt + (brow0 + row) * K + k0 + kq * 8, bufB + dst);
    }
  };
  auto compute = [&](const bf16* bufA, const bf16* bufB) {
    short8 af[4], bfr[4];
    #pragma unroll
    for (int m = 0; m < 4; ++m) af[m] = *(const short8*)&bufA[(wm * 64 + m * 16 + lr) * 32 + hi * 8];
    #pragma unroll
    for (int n = 0; n < 4; ++n) bfr[n] = *(const short8*)&bufB[(wn * 64 + n * 16 + lr) * 32 + hi * 8];
    #pragma unroll
    for (int m = 0; m < 4; ++m)
      #pragma unroll
      for (int n = 0; n < 4; ++n)
        acc[m][n] = mfma16x16x32(af[m], bfr[n], acc[m][n]);
  };

  const int nt = K >> 5;               // even (24 or 96)
  stage(lA0, lB0, 0);
  __syncthreads();
  for (int t = 0; t < nt; t += 2) {
    if (t + 1 < nt) stage(lA1, lB1, t + 1);
    compute(lA0, lB0);
    __syncthreads();
    if (t + 2 < nt) stage(lA0, lB0, t + 2);
    compute(lA1, lB1);
    __syncthreads();
  }

  if constexpr (EPI == 0 || EPI == 2) {
    // ---- LDS-staged coalesced bf16 epilogue ----
    bf16* ct = SMEM;                   // 128x128 bf16 tile, XOR-swizzled rows
    #pragma unroll
    for (int n = 0; n < 4; ++n) {
      const int col = wn * 64 + n * 16 + lr;         // tile-local
      const float bv = bias[(int)brow0 + col];
      #pragma unroll
      for (int m = 0; m < 4; ++m) {
        #pragma unroll
        for (int e = 0; e < 4; ++e) {
          const int row = wm * 64 + m * 16 + hi * 4 + e;
          float v = acc[m][n][e] + bv;
          if constexpr (EPI == 2) v = gelu_f(v);
          const int byte = (row << 8) + (col << 1);
          *(bf16*)((char*)ct + (byte ^ ((row & 7) << 5))) = __float2bfloat16(v);
        }
      }
    }
    __syncthreads();
    if constexpr (EPI == 0) {
      if ((int)brow0 >= 1536) {
        // ---- V third: transposed drain -> V^T [head][64][MPAD] ----
        const int head_base = ((int)brow0 >> 6) % 12;
        #pragma unroll
        for (int i = 0; i < 8; ++i) {
          const int idx = i * 256 + tid;          // 0..2047 (16-B units)
          const int dl = idx >> 4;                // 0..127  (tile col = d-lane)
          const int h2 = dl >> 6, d = dl & 63;
          const int tg = (idx & 15) * 8;          // token-group base (8 tokens)
          union { bf16 h[8]; short8 v; } u8;
          #pragma unroll
          for (int j = 0; j < 8; ++j) {
            const int tok = tg + j;
            const int byte = (tok << 8) + (dl << 1);
            u8.h[j] = *(const bf16*)((const char*)ct + (byte ^ ((tok & 7) << 5)));
          }
          *(short8*)&ob2[((size_t)(head_base + h2) * 64 + d) * MPAD + arow0 + tg] = u8.v;
        }
      } else {
        // ---- q/k thirds: token-major drain ----
        #pragma unroll
        for (int i = 0; i < 8; ++i) {
          const int lin16 = i * 256 + tid;
          const int row = lin16 >> 4;
          const int u   = lin16 & 15;
          const int byte = (row << 8) + (u << 4);
          const short8 val = *(const short8*)((char*)ct + (byte ^ ((row & 7) << 5)));
          const int grow = (int)arow0 + row;
          const int gcol = (int)brow0 + u * 8;
          if (grow < Mreal) {
            const int which = gcol / 768, head = (gcol >> 6) % 12, d = gcol & 63;
            bf16* dstb = (which == 0) ? ob0 : ob1;
            *(short8*)&dstb[((size_t)head * MPAD + grow) * 64 + d] = val;
          }
        }
      }
    } else {
      #pragma unroll
      for (int i = 0; i < 8; ++i) {
        const int lin16 = i * 256 + tid;
        const int row = lin16 >> 4;
        const int u   = lin16 & 15;
        const int byte = (row << 8) + (u << 4);
        const short8 val = *(const short8*)((char*)ct + (byte ^ ((row & 7) << 5)));
        *(short8*)&ob0[(size_t)((int)arow0 + row) * 3072 + (int)brow0 + u * 8] = val;
      }
    }
  } else {
    // ---- f32 residual epilogues (direct) ----
    #pragma unroll
    for (int n = 0; n < 4; ++n) {
      const int col = (int)brow0 + wn * 64 + n * 16 + lr;
      const float bv = bias[col];
      #pragma unroll
      for (int m = 0; m < 4; ++m) {
        #pragma unroll
        for (int e = 0; e < 4; ++e) {
          const int row = (int)arow0 + wm * 64 + m * 16 + hi * 4 + e;
          const float v = acc[m][n][e] + bv;
          if constexpr (EPI == 1) {
            if (row < Mreal) {
              const int win = row / 196, tok = row % 196;
              const int b_ = win / 25, wh = (win / 5) % 5, ww = win % 5;
              const int i = tok / 14, j = tok % 14;
              const int h = wh * 14 + i, w = ww * 14 + j;
              if (h < 64 && w < 64) {
                const size_t idx = ((size_t)((b_ * 64 + h) * 64 + w)) * 768 + col;
                fout[idx] = fin[idx] + v;
              }
            }
          } else {
            const size_t idx = (size_t)row * 768 + col;
            fout[idx] = fin[idx] + v;
          }
        }
      }
    }
  }
}

// ---------------- fused window attention, one block per (window, head) -------
// q/k: [head][MPAD][64] token-major; V^T: [head][64][MPAD] d-major (from qkv).
// No K/V LDS staging: K-frags and V^T-frags are contiguous 16-B global reads
// (L1/L2-resident; lesson: don't stage what cache fits). LDS = 38144 B:
//   phase A: pbh[0,4096) pbw[4096,8192) Gh[8192,23168) Gw[23168,38144)
//   main:    relh_s[0,5488) relw_s[5488,10976)   (aliased over dead phase A)
__global__ __launch_bounds__(256, 3)
void attn_kernel(const bf16* __restrict__ qb, const bf16* __restrict__ kb,
                 const bf16* __restrict__ vtg_all, const float* __restrict__ rph,
                 const float* __restrict__ rpw, bf16* __restrict__ aout) {
  __shared__ __align__(16) char SM[38144];
  bf16* pbh    = (bf16*)SM;
  bf16* pbw    = (bf16*)(SM + 4096);
  bf16* Gh     = (bf16*)(SM + 8192);
  bf16* Gw     = (bf16*)(SM + 23168);
  bf16* relh_s = (bf16*)SM;             // [196][14], written after phase A dies
  bf16* relw_s = (bf16*)(SM + 5488);

  const int bh = blockIdx.x;             // 0..2399
  const int win = bh / 12, head = bh % 12;
  const size_t base = ((size_t)head * MPAD + win * 196) * 64;
  const bf16* Q   = qb + base;
  const bf16* Kp  = kb + base;
  const bf16* Vt  = vtg_all + (size_t)head * 64 * MPAD + win * 196;  // [d][tok]
  const int tid = threadIdx.x, lane = tid & 63, wv = tid >> 6;
  const int lr = lane & 15, hi = lane >> 4;

  // ---- stage rel_pos (bf16, zero-padded to 32 rows) ----
  for (int i = tid; i < 32 * 64; i += 256) {
    const int r = i >> 6, c = i & 63;
    const bool ok = r < 27;
    pbh[i] = __float2bfloat16(ok ? rph[r * 64 + c] : 0.f);
    pbw[i] = __float2bfloat16(ok ? rpw[r * 64 + c] : 0.f);
  }
  __syncthreads();
  // ---- phase A: G = Q @ relpos^T via MFMA ----
  {
    short8 bh00 = *(const short8*)&pbh[(lr) * 64 + hi * 8];
    short8 bh01 = *(const short8*)&pbh[(lr) * 64 + 32 + hi * 8];
    short8 bh10 = *(const short8*)&pbh[(16 + lr) * 64 + hi * 8];
    short8 bh11 = *(const short8*)&pbh[(16 + lr) * 64 + 32 + hi * 8];
    short8 bw00 = *(const short8*)&pbw[(lr) * 64 + hi * 8];
    short8 bw01 = *(const short8*)&pbw[(lr) * 64 + 32 + hi * 8];
    short8 bw10 = *(const short8*)&pbw[(16 + lr) * 64 + hi * 8];
    short8 bw11 = *(const short8*)&pbw[(16 + lr) * 64 + 32 + hi * 8];
    for (int mt = wv; mt < 13; mt += 4) {
      const short8 a0 = *(const short8*)&Q[(mt * 16 + lr) * 64 + hi * 8];
      const short8 a1 = *(const short8*)&Q[(mt * 16 + lr) * 64 + 32 + hi * 8];
      f32x4 g0 = {}, g1 = {}, g2 = {}, g3 = {};
      g0 = mfma16x16x32(a0, bh00, g0); g0 = mfma16x16x32(a1, bh01, g0);
      g1 = mfma16x16x32(a0, bh10, g1); g1 = mfma16x16x32(a1, bh11, g1);
      g2 = mfma16x16x32(a0, bw00, g2); g2 = mfma16x16x32(a1, bw01, g2);
      g3 = mfma16x16x32(a0, bw10, g3); g3 = mfma16x16x32(a1, bw11, g3);
      #pragma unroll
      for (int e = 0; e < 4; ++e) {
        const int row = mt * 16 + hi * 4 + e;
        Gh[row * 36 + lr]      = __float2bfloat16(g0[e]);
        Gh[row * 36 + 16 + lr] = __float2bfloat16(g1[e]);
        Gw[row * 36 + lr]      = __float2bfloat16(g2[e]);
        Gw[row * 36 + 16 + lr] = __float2bfloat16(g3[e]);
      }
    }
  }
  __syncthreads();
  // ---- gather G -> regs ----
  bf16 ghr[11], gwr[11];
  #pragma unroll
  for (int t = 0; t < 11; ++t) {
    const int i = tid + t * 256;
    if (i < 196 * 14) {
      const int q = i / 14, kk = i - (i / 14) * 14;
      const int rh = q / 14 - kk + 13;
      const int rw2 = q - (q / 14) * 14 - kk + 13;
      ghr[t] = Gh[q * 36 + rh];
      gwr[t] = Gw[q * 36 + rw2];
    }
  }
  __syncthreads();
  // ---- write rel tables (over dead phase-A region) ----
  #pragma unroll
  for (int t = 0; t < 11; ++t) {
    const int i = tid + t * 256;
    if (i < 196 * 14) { relh_s[i] = ghr[t]; relw_s[i] = gwr[t]; }
  }
  __syncthreads();

  // ---- main loop over q-tiles ----
  for (int qt = wv; qt < 13; qt += 4) {
    const int q = qt * 16 + lr;
    const int qc = q < 196 ? q : 195;
    const short8 bq0 = *(const short8*)&Q[(qt * 16 + lr) * 64 + hi * 8];
    const short8 bq1 = *(const short8*)&Q[(qt * 16 + lr) * 64 + 32 + hi * 8];
    // S^T = K . Q^T  (13 key tiles of 16; K-frags straight from global)
    f32x4 s[14];
    __builtin_amdgcn_s_setprio(1);
    #pragma unroll
    for (int nt = 0; nt < 13; ++nt) {
      const int key = nt * 16 + lr;
      const short8 ka0 = *(const short8*)&Kp[key * 64 + hi * 8];
      const short8 ka1 = *(const short8*)&Kp[key * 64 + 32 + hi * 8];
      f32x4 z = {};
      z = mfma16x16x32(ka0, bq0, z);
      z = mfma16x16x32(ka1, bq1, z);
      s[nt] = z;
    }
    __builtin_amdgcn_s_setprio(0);
    float mx = -3.0e38f;
    #pragma unroll
    for (int nt = 0; nt < 13; ++nt) {
      #pragma unroll
      for (int e = 0; e < 4; ++e) {
        const int key = nt * 16 + hi * 4 + e;
        const int kh = key / 14, kw = key - kh * 14;
        float v = s[nt][e] * 0.125f + __bfloat162float(relh_s[qc * 14 + kh])
                                    + __bfloat162float(relw_s[qc * 14 + kw]);
        v = (key < 196) ? v : -3.0e38f;
        s[nt][e] = v;
        mx = fmaxf(mx, v);
      }
    }
    mx = fmaxf(mx, __shfl_xor(mx, 16));
    mx = fmaxf(mx, __shfl_xor(mx, 32));
    float sm = 0.f;
    #pragma unroll
    for (int nt = 0; nt < 13; ++nt)
      #pragma unroll
      for (int e = 0; e < 4; ++e) {
        const float p = __expf(s[nt][e] - mx);
        s[nt][e] = p; sm += p;
      }
    sm += __shfl_xor(sm, 16);
    sm += __shfl_xor(sm, 32);
    const float rinv = 1.f / sm;
    s[13] = f32x4{0.f, 0.f, 0.f, 0.f};   // keys 208..223: P = 0 exactly
    // O^T = V^T . P^T  (7 key chunks of 32); P frag built in-register
    f32x4 o[4] = {};
    #pragma unroll
    for (int kk = 0; kk < 7; ++kk) {
      const uint32_t x0 = cvtpk(s[2 * kk][0] * rinv, s[2 * kk][1] * rinv);
      const uint32_t x1 = cvtpk(s[2 * kk][2] * rinv, s[2 * kk][3] * rinv);
      const uint32_t y0 = cvtpk(s[2 * kk + 1][0] * rinv, s[2 * kk + 1][1] * rinv);
      const uint32_t y1 = cvtpk(s[2 * kk + 1][2] * rinv, s[2 * kk + 1][3] * rinv);
      const uint32_t s0 = (hi < 2) ? y0 : x0, s1 = (hi < 2) ? y1 : x1;
      const uint32_t t0 = __shfl_xor(s0, 32), t1 = __shfl_xor(s1, 32);
      const uint32_t o0 = (hi < 2) ? x0 : y0, o1 = (hi < 2) ? x1 : y1;
      const bool sendOwn = (hi == 1) || (hi == 2);
      const uint32_t u0 = sendOwn ? o0 : t0, u1 = sendOwn ? o1 : t1;
      const uint32_t r0 = __shfl_xor(u0, 16), r1 = __shfl_xor(u1, 16);
      union { uint32_t u[4]; short8 v; } pf;
      pf.u[0] = (hi == 0) ? x0 : ((hi == 2) ? t0 : r0);
      pf.u[1] = (hi == 0) ? x1 : ((hi == 2) ? t1 : r1);
      pf.u[2] = (hi == 3) ? y0 : ((hi == 1) ? t0 : r0);
      pf.u[3] = (hi == 3) ? y1 : ((hi == 1) ? t1 : r1);
      __builtin_amdgcn_s_setprio(1);
      #pragma unroll
      for (int n2 = 0; n2 < 4; ++n2) {
        const int d = n2 * 16 + lr;
        const short8 va = *(const short8*)&Vt[(size_t)d * MPAD + kk * 32 + hi * 8];
        o[n2] = mfma16x16x32(va, pf.v, o[n2]);
      }
      __builtin_amdgcn_s_setprio(0);
    }
    if (q < 196) {
      bf16* orow = aout + ((size_t)head * MPAD + win * 196 + q) * 64;
      #pragma unroll
      for (int n2 = 0; n2 < 4; ++n2) {
        uint32_t d0 = cvtpk(o[n2][0], o[n2][1]);
        uint32_t d1 = cvtpk(o[n2][2], o[n2][3]);
        uint32_t* dst = (uint32_t*)&orow[n2 * 16 + hi * 4];
        dst[0] = d0; dst[1] = d1;
      }
    }
  }
}

// ---------------- host ----------------
extern "C" void kernel_launch(void* const* d_in, const int* in_sizes, int n_in,
                              void* d_out, int out_size, void* d_ws, size_t ws_size,
                              hipStream_t stream) {
  (void)in_sizes; (void)n_in; (void)out_size; (void)ws_size;
  const float* x      = (const float*)d_in[0];
  const float* ln1_g  = (const float*)d_in[1];
  const float* ln1_b  = (const float*)d_in[2];
  const float* qkv_w  = (const float*)d_in[3];
  const float* qkv_b  = (const float*)d_in[4];
  const float* proj_w = (const float*)d_in[5];
  const float* proj_b = (const float*)d_in[6];
  const float* rph    = (const float*)d_in[7];
  const float* rpw    = (const float*)d_in[8];
  const float* ln2_g  = (const float*)d_in[9];
  const float* ln2_b  = (const float*)d_in[10];
  const float* w1     = (const float*)d_in[11];
  const float* b1v    = (const float*)d_in[12];
  const float* w2     = (const float*)d_in[13];
  const float* b2v    = (const float*)d_in[14];
  float* outp = (float*)d_out;   // also serves as x1 (written by proj epilogue)

  char* ws = (char*)d_ws;
  size_t off = 0;
  auto alloc = [&](size_t bytes) { char* p = ws + off; off += (bytes + 255) & ~(size_t)255; return p; };
  bf16* qkv_wt  = (bf16*)alloc((size_t)2304 * 768 * 2);
  bf16* proj_wt = (bf16*)alloc((size_t)768 * 768 * 2);
  bf16* w1t     = (bf16*)alloc((size_t)3072 * 768 * 2);
  bf16* w2t     = (bf16*)alloc((size_t)768 * 3072 * 2);
  const size_t szB1 = (size_t)MPAD * 768 * 2;
  const size_t szB2 = (size_t)TOK2 * 768 * 2;
  char* regB = alloc(szB1 > szB2 ? szB1 : szB2);
  const size_t szQKV = (size_t)3 * 12 * MPAD * 64 * 2;
  const size_t szH   = (size_t)TOK2 * 3072 * 2;
  char* regC = alloc(szQKV > szH ? szQKV : szH);

  bf16* xnwin   = (bf16*)regB;
  bf16* attnout = (bf16*)regB;
  bf16* xn2     = (bf16*)regB;
  bf16* qbuf    = (bf16*)regC;                       // [12][MPAD][64]
  bf16* kbuf    = qbuf + (size_t)12 * MPAD * 64;     // [12][MPAD][64]
  bf16* vbuf_t  = kbuf + (size_t)12 * MPAD * 64;     // [12][64][MPAD]  (V^T)
  bf16* hbuf    = (bf16*)regC;

  transpose_cast<<<dim3(2304 / 32, 768 / 32), 256, 0, stream>>>(qkv_w, qkv_wt, 768, 2304);
  transpose_cast<<<dim3(768 / 32, 768 / 32), 256, 0, stream>>>(proj_w, proj_wt, 768, 768);
  transpose_cast<<<dim3(3072 / 32, 768 / 32), 256, 0, stream>>>(w1, w1t, 768, 3072);
  transpose_cast<<<dim3(768 / 32, 3072 / 32), 256, 0, stream>>>(w2, w2t, 3072, 768);

  ln1_partition<<<dim3(MROWS / 4), 256, 0, stream>>>(x, ln1_g, ln1_b, xnwin);

  gemm_bf16<0><<<dim3(2304 / 128, MPAD / 128), 256, 0, stream>>>(
      xnwin, qkv_wt, qkv_b, 768, MROWS, nullptr, nullptr, qbuf, kbuf, vbuf_t);

  attn_kernel<<<dim3(2400), 256, 0, stream>>>(qbuf, kbuf, vbuf_t, rph, rpw, attnout);

  gemm_bf16<1><<<dim3(768 / 128, MPAD / 128), 256, 0, stream>>>(
      attnout, proj_wt, proj_b, 768, MROWS, x, outp, nullptr, nullptr, nullptr);

  ln2_kernel<<<dim3(TOK2 / 4), 256, 0, stream>>>(outp, ln2_g, ln2_b, xn2);

  gemm_bf16<2><<<dim3(3072 / 128, TOK2 / 128), 256, 0, stream>>>(
      xn2, w1t, b1v, 768, TOK2, nullptr, nullptr, hbuf, nullptr, nullptr);
  gemm_bf16<3><<<dim3(768 / 128, TOK2 / 128), 256, 0, stream>>>(
      hbuf, w2t, b2v, 3072, TOK2, outp, outp, nullptr, nullptr, nullptr);
}

// Round 11
// 1305.821 us; speedup vs baseline: 1.0276x; 1.0276x over previous
//
#include <hip/hip_runtime.h>
#include <hip/hip_bf16.h>
#include <cstdint>
#include <cstddef>

using bf16 = __hip_bfloat16;
typedef __attribute__((ext_vector_type(8))) short short8;
typedef __attribute__((ext_vector_type(4))) float f32x4;

typedef __attribute__((address_space(1))) const void as1_void;
typedef __attribute__((address_space(3))) void as3_void;

__device__ __forceinline__ f32x4 mfma16x16x32(short8 a, short8 b, f32x4 c) {
  return __builtin_amdgcn_mfma_f32_16x16x32_bf16(a, b, c, 0, 0, 0);
}

__device__ __forceinline__ void gload_lds16(const void* g, void* l) {
  __builtin_amdgcn_global_load_lds((as1_void*)g, (as3_void*)l, 16, 0, 0);
}

__device__ __forceinline__ uint32_t cvtpk(float a, float b) {
  uint32_t r;
  asm("v_cvt_pk_bf16_f32 %0, %1, %2" : "=v"(r) : "v"(a), "v"(b));
  return r;
}

__device__ __forceinline__ float gelu_f(float v) {
  const float u = 0.7978845608f * v * (1.f + 0.044715f * v * v);
  const float e = __expf(-2.f * fabsf(u));
  const float t = (1.f - e) / (1.f + e);
  return 0.5f * v * (1.f + (u < 0.f ? -t : t));
}

// ---------------- problem constants ----------------
static constexpr int MROWS = 39200;
static constexpr int MPAD  = 39296;
static constexpr int TOK2  = 32768;

// ---------------- weight transpose+cast:  in f32 [K][N] -> out bf16 [N][K] ----
__global__ __launch_bounds__(256)
void transpose_cast(const float* __restrict__ in, bf16* __restrict__ out, int K, int N) {
  __shared__ float t[32][33];
  const int tx = threadIdx.x & 31, ty = threadIdx.x >> 5;
  const int bx = blockIdx.x, by = blockIdx.y;
  const int x = bx * 32 + tx;
  for (int r = ty; r < 32; r += 8)
    t[r][tx] = in[(size_t)(by * 32 + r) * N + x];
  __syncthreads();
  const int xo = by * 32 + tx;
  for (int r = ty; r < 32; r += 8)
    out[(size_t)(bx * 32 + r) * K + xo] = __float2bfloat16(t[tx][r]);
}

// ---------------- LN1 + window partition -> bf16 [MPAD][768] ----------------
__global__ __launch_bounds__(256)
void ln1_partition(const float* __restrict__ x, const float* __restrict__ g,
                   const float* __restrict__ bb, bf16* __restrict__ out) {
  const int token = blockIdx.x * 4 + (threadIdx.x >> 6);
  const int lane = threadIdx.x & 63;
  const int win = token / 196, tok = token % 196;
  const int b_ = win / 25, wh = (win / 5) % 5, ww = win % 5;
  const int i = tok / 14, j = tok % 14;
  const int h = wh * 14 + i, w = ww * 14 + j;
  bf16* o = out + (size_t)token * 768;
  if (h >= 64 || w >= 64) {
    for (int t = 0; t < 12; ++t) o[lane + 64 * t] = __float2bfloat16(0.f);
    return;
  }
  const float* src = x + ((size_t)((b_ * 64 + h) * 64 + w)) * 768;
  float vals[12], s = 0.f, ss = 0.f;
  #pragma unroll
  for (int t = 0; t < 12; ++t) {
    float v = src[lane + 64 * t];
    vals[t] = v; s += v; ss += v * v;
  }
  #pragma unroll
  for (int d = 32; d > 0; d >>= 1) { s += __shfl_xor(s, d); ss += __shfl_xor(ss, d); }
  const float mu = s * (1.f / 768.f);
  const float var = ss * (1.f / 768.f) - mu * mu;
  const float inv = rsqrtf(var + 1e-6f);
  #pragma unroll
  for (int t = 0; t < 12; ++t) {
    const int c = lane + 64 * t;
    o[c] = __float2bfloat16((vals[t] - mu) * inv * g[c] + bb[c]);
  }
}

// ---------------- LN2 on x1 (f32, dense [32768][768]) -> bf16 ----------------
__global__ __launch_bounds__(256)
void ln2_kernel(const float* __restrict__ x1, const float* __restrict__ g,
                const float* __restrict__ bb, bf16* __restrict__ out) {
  const int token = blockIdx.x * 4 + (threadIdx.x >> 6);
  const int lane = threadIdx.x & 63;
  const float* src = x1 + (size_t)token * 768;
  bf16* o = out + (size_t)token * 768;
  float vals[12], s = 0.f, ss = 0.f;
  #pragma unroll
  for (int t = 0; t < 12; ++t) {
    float v = src[lane + 64 * t];
    vals[t] = v; s += v; ss += v * v;
  }
  #pragma unroll
  for (int d = 32; d > 0; d >>= 1) { s += __shfl_xor(s, d); ss += __shfl_xor(ss, d); }
  const float mu = s * (1.f / 768.f);
  const float var = ss * (1.f / 768.f) - mu * mu;
  const float inv = rsqrtf(var + 1e-6f);
  #pragma unroll
  for (int t = 0; t < 12; ++t) {
    const int c = lane + 64 * t;
    o[c] = __float2bfloat16((vals[t] - mu) * inv * g[c] + bb[c]);
  }
}

// ---------------- generic bf16 GEMM, 128x128 tile, BK=32, 2-phase dbuf ------
// (r5/r6-proven structure; counted-vmcnt confirmed null at 2-phase)
// EPI 0: qkv -> q/k/v [head][MPAD][64] (LDS-staged stores)
// EPI 1: proj (A in [head][MPAD][64]) + unpartition + residual (f32)
// EPI 2: gelu -> bf16 [M][3072] (LDS-staged stores)
// EPI 3: dense residual add (f32)
template<int EPI>
__global__ __launch_bounds__(256)
void gemm_bf16(const bf16* __restrict__ A, const bf16* __restrict__ Bt,
               const float* __restrict__ bias, int K, int Mreal,
               const float* __restrict__ fin, float* __restrict__ fout,
               bf16* __restrict__ ob0, bf16* __restrict__ ob1, bf16* __restrict__ ob2) {
  __shared__ __align__(16) bf16 SMEM[16384];                 // 32 KB
  bf16* const lA0 = SMEM;
  bf16* const lA1 = SMEM + 4096;
  bf16* const lB0 = SMEM + 8192;
  bf16* const lB1 = SMEM + 12288;
  const int tid = threadIdx.x;
  const int lane = tid & 63, wv = tid >> 6;
  const int lr = lane & 15, hi = lane >> 4;
  const int wm = wv >> 1, wn = wv & 1;

  // bijective chunked XCD swizzle (m204)
  const int gx = gridDim.x;
  const int nwg = gx * gridDim.y;
  int lin = blockIdx.y * gx + blockIdx.x;
  {
    const int q8 = nwg >> 3, r8 = nwg & 7;
    const int xcd = lin & 7, pos = lin >> 3;
    lin = (xcd < r8 ? xcd * (q8 + 1) : r8 * (q8 + 1) + (xcd - r8) * q8) + pos;
  }
  const size_t arow0 = (size_t)(lin / gx) * 128;
  const size_t brow0 = (size_t)(lin % gx) * 128;
  f32x4 acc[4][4] = {};

  auto stage = [&](bf16* bufA, bf16* bufB, int kt) {
    const int k0 = kt * 32;
    #pragma unroll
    for (int it = 0; it < 2; ++it) {
      const int seg = it * 256 + tid;
      const int row = seg >> 2, kq = seg & 3;
      const size_t dst = (size_t)(it * 256 + wv * 64) * 8;
      if constexpr (EPI == 1) {
        const int k = k0 + kq * 8;   // A layout: [head][MPAD][64]
        gload_lds16(A + ((size_t)(k >> 6) * MPAD + arow0 + row) * 64 + (k & 63), bufA + dst);
      } else {
        gload_lds16(A + (arow0 + row) * K + k0 + kq * 8, bufA + dst);
      }
      gload_lds16(Bt + (brow0 + row) * K + k0 + kq * 8, bufB + dst);
    }
  };
  auto compute = [&](const bf16* bufA, const bf16* bufB) {
    short8 af[4], bfr[4];
    #pragma unroll
    for (int m = 0; m < 4; ++m) af[m] = *(const short8*)&bufA[(wm * 64 + m * 16 + lr) * 32 + hi * 8];
    #pragma unroll
    for (int n = 0; n < 4; ++n) bfr[n] = *(const short8*)&bufB[(wn * 64 + n * 16 + lr) * 32 + hi * 8];
    #pragma unroll
    for (int m = 0; m < 4; ++m)
      #pragma unroll
      for (int n = 0; n < 4; ++n)
        acc[m][n] = mfma16x16x32(af[m], bfr[n], acc[m][n]);
  };

  const int nt = K >> 5;               // even (24 or 96)
  stage(lA0, lB0, 0);
  __syncthreads();
  for (int t = 0; t < nt; t += 2) {
    if (t + 1 < nt) stage(lA1, lB1, t + 1);
    compute(lA0, lB0);
    __syncthreads();
    if (t + 2 < nt) stage(lA0, lB0, t + 2);
    compute(lA1, lB1);
    __syncthreads();
  }

  if constexpr (EPI == 0 || EPI == 2) {
    // ---- LDS-staged coalesced bf16 epilogue ----
    bf16* ct = SMEM;                   // 128x128 bf16 tile, XOR-swizzled rows
    #pragma unroll
    for (int n = 0; n < 4; ++n) {
      const int col = wn * 64 + n * 16 + lr;         // tile-local
      const float bv = bias[(int)brow0 + col];
      #pragma unroll
      for (int m = 0; m < 4; ++m) {
        #pragma unroll
        for (int e = 0; e < 4; ++e) {
          const int row = wm * 64 + m * 16 + hi * 4 + e;
          float v = acc[m][n][e] + bv;
          if constexpr (EPI == 2) v = gelu_f(v);
          const int byte = (row << 8) + (col << 1);
          *(bf16*)((char*)ct + (byte ^ ((row & 7) << 5))) = __float2bfloat16(v);
        }
      }
    }
    __syncthreads();
    #pragma unroll
    for (int i = 0; i < 8; ++i) {
      const int lin16 = i * 256 + tid;           // 16-B unit index
      const int row = lin16 >> 4;
      const int u   = lin16 & 15;
      const int byte = (row << 8) + (u << 4);
      const short8 val = *(const short8*)((char*)ct + (byte ^ ((row & 7) << 5)));
      const int grow = (int)arow0 + row;
      const int gcol = (int)brow0 + u * 8;
      if constexpr (EPI == 0) {
        if (grow < Mreal) {
          const int which = gcol / 768, head = (gcol >> 6) % 12, d = gcol & 63;
          bf16* dstb = (which == 0) ? ob0 : ((which == 1) ? ob1 : ob2);
          *(short8*)&dstb[((size_t)head * MPAD + grow) * 64 + d] = val;
        }
      } else {
        *(short8*)&ob0[(size_t)grow * 3072 + gcol] = val;
      }
    }
  } else {
    // ---- f32 residual epilogues (direct) ----
    #pragma unroll
    for (int n = 0; n < 4; ++n) {
      const int col = (int)brow0 + wn * 64 + n * 16 + lr;
      const float bv = bias[col];
      #pragma unroll
      for (int m = 0; m < 4; ++m) {
        #pragma unroll
        for (int e = 0; e < 4; ++e) {
          const int row = (int)arow0 + wm * 64 + m * 16 + hi * 4 + e;
          const float v = acc[m][n][e] + bv;
          if constexpr (EPI == 1) {
            if (row < Mreal) {
              const int win = row / 196, tok = row % 196;
              const int b_ = win / 25, wh = (win / 5) % 5, ww = win % 5;
              const int i = tok / 14, j = tok % 14;
              const int h = wh * 14 + i, w = ww * 14 + j;
              if (h < 64 && w < 64) {
                const size_t idx = ((size_t)((b_ * 64 + h) * 64 + w)) * 768 + col;
                fout[idx] = fin[idx] + v;
              }
            }
          } else {
            const size_t idx = (size_t)row * 768 + col;
            fout[idx] = fin[idx] + v;
          }
        }
      }
    }
  }
}

// ---------------- fused window attention, one block per (window, head) -------
// 512 threads (8 waves) over the same 65 KB LDS -> 16 waves/CU (2x occupancy
// vs 256-thread version; VGPR-84 cap = 4 waves/SIMD).
// q/k/v/aout in [head][MPAD][64]; K LDS-staged swizzled (gload_lds with
// pre-swizzled source), V^T LDS-staged swizzled; P in-register (cvt_pk+shfl).
__global__ __launch_bounds__(512, 4)
void attn_kernel(const bf16* __restrict__ qb, const bf16* __restrict__ kb,
                 const bf16* __restrict__ vb, const float* __restrict__ rph,
                 const float* __restrict__ rpw, bf16* __restrict__ aout) {
  __shared__ __align__(16) char SM[65248];
  bf16* pbh    = (bf16*)SM;
  bf16* pbw    = (bf16*)(SM + 4096);
  bf16* Gh     = (bf16*)(SM + 8192);
  bf16* Gw     = (bf16*)(SM + 23168);
  char* klds   = SM;                    // [200 rows][128 B], XOR-swizzled
  char* vtb    = SM + 25600;            // [64 d][448 B], XOR-swizzled
  bf16* relh_s = (bf16*)(SM + 54272);   // [196][14]
  bf16* relw_s = (bf16*)(SM + 59760);   // [196][14]

  const int bh = blockIdx.x;             // 0..2399
  const int win = bh / 12, head = bh % 12;
  const size_t base = ((size_t)head * MPAD + win * 196) * 64;
  const bf16* Q  = qb + base;
  const bf16* Kp = kb + base;
  const bf16* Vp = vb + base;
  const int tid = threadIdx.x, lane = tid & 63, wv = tid >> 6;   // wv 0..7
  const int lr = lane & 15, hi = lane >> 4;

  // ---- stage rel_pos (bf16, zero-padded to 32 rows) ----
  for (int i = tid; i < 32 * 64; i += 512) {
    const int r = i >> 6, c = i & 63;
    const bool ok = r < 27;
    pbh[i] = __float2bfloat16(ok ? rph[r * 64 + c] : 0.f);
    pbw[i] = __float2bfloat16(ok ? rpw[r * 64 + c] : 0.f);
  }
  __syncthreads();
  // ---- phase A: G = Q @ relpos^T via MFMA ----
  {
    short8 bh00 = *(const short8*)&pbh[(lr) * 64 + hi * 8];
    short8 bh01 = *(const short8*)&pbh[(lr) * 64 + 32 + hi * 8];
    short8 bh10 = *(const short8*)&pbh[(16 + lr) * 64 + hi * 8];
    short8 bh11 = *(const short8*)&pbh[(16 + lr) * 64 + 32 + hi * 8];
    short8 bw00 = *(const short8*)&pbw[(lr) * 64 + hi * 8];
    short8 bw01 = *(const short8*)&pbw[(lr) * 64 + 32 + hi * 8];
    short8 bw10 = *(const short8*)&pbw[(16 + lr) * 64 + hi * 8];
    short8 bw11 = *(const short8*)&pbw[(16 + lr) * 64 + 32 + hi * 8];
    for (int mt = wv; mt < 13; mt += 8) {
      const short8 a0 = *(const short8*)&Q[(mt * 16 + lr) * 64 + hi * 8];
      const short8 a1 = *(const short8*)&Q[(mt * 16 + lr) * 64 + 32 + hi * 8];
      f32x4 g0 = {}, g1 = {}, g2 = {}, g3 = {};
      g0 = mfma16x16x32(a0, bh00, g0); g0 = mfma16x16x32(a1, bh01, g0);
      g1 = mfma16x16x32(a0, bh10, g1); g1 = mfma16x16x32(a1, bh11, g1);
      g2 = mfma16x16x32(a0, bw00, g2); g2 = mfma16x16x32(a1, bw01, g2);
      g3 = mfma16x16x32(a0, bw10, g3); g3 = mfma16x16x32(a1, bw11, g3);
      #pragma unroll
      for (int e = 0; e < 4; ++e) {
        const int row = mt * 16 + hi * 4 + e;
        Gh[row * 36 + lr]      = __float2bfloat16(g0[e]);
        Gh[row * 36 + 16 + lr] = __float2bfloat16(g1[e]);
        Gw[row * 36 + lr]      = __float2bfloat16(g2[e]);
        Gw[row * 36 + 16 + lr] = __float2bfloat16(g3[e]);
      }
    }
  }
  __syncthreads();
  // ---- gather G -> regs ----
  bf16 ghr[6], gwr[6];
  #pragma unroll
  for (int t = 0; t < 6; ++t) {
    const int i = tid + t * 512;
    if (i < 196 * 14) {
      const int q = i / 14, kk = i - (i / 14) * 14;
      const int rh = q / 14 - kk + 13;
      const int rw2 = q - (q / 14) * 14 - kk + 13;
      ghr[t] = Gh[q * 36 + rh];
      gwr[t] = Gw[q * 36 + rw2];
    }
  }
  __syncthreads();
  // ---- write rel tables; stage K (swizzled gload_lds); stage V^T ----
  #pragma unroll
  for (int t = 0; t < 6; ++t) {
    const int i = tid + t * 512;
    if (i < 196 * 14) { relh_s[i] = ghr[t]; relw_s[i] = gwr[t]; }
  }
  for (int c = wv; c < 25; c += 8) {          // 25 chunks x 1024 B = 200 K-rows
    const int row = c * 8 + (lane >> 3);
    const int ch  = (lane & 7) ^ (row & 7);   // pre-swizzled global source
    gload_lds16(Kp + row * 64 + ch * 8, klds + c * 1024);
  }
  for (int i = tid; i < 196 * 8; i += 512) {  // V^T staging (vectorized read)
    const int key = i >> 3, dg = (i & 7) * 8;
    const short8 v = *(const short8*)&Vp[key * 64 + dg];
    #pragma unroll
    for (int j = 0; j < 8; ++j) {
      const int idx = (dg + j) * 448 + key * 2;
      *(bf16*)(vtb + (idx ^ (j << 4))) = ((const bf16*)&v)[j];
    }
  }
  for (int i = tid; i < 64 * 28; i += 512) {  // zero-pad keys 196..223
    const int d = i / 28, key = 196 + i - (i / 28) * 28;
    const int idx = d * 448 + key * 2;
    *(bf16*)(vtb + (idx ^ ((d & 7) << 4))) = __float2bfloat16(0.f);
  }
  __syncthreads();

  // ---- main loop over q-tiles (8 waves cover 13 tiles) ----
  for (int qt = wv; qt < 13; qt += 8) {
    const int q = qt * 16 + lr;               // this lane's q-row
    const int qc = q < 196 ? q : 195;
    const short8 bq0 = *(const short8*)&Q[(qt * 16 + lr) * 64 + hi * 8];
    const short8 bq1 = *(const short8*)&Q[(qt * 16 + lr) * 64 + 32 + hi * 8];
    // S^T = K . Q^T  (13 key tiles of 16)
    f32x4 s[14];
    __builtin_amdgcn_s_setprio(1);
    #pragma unroll
    for (int nt = 0; nt < 13; ++nt) {
      const int key = nt * 16 + lr;
      const char* kr = klds + key * 128;
      const short8 ka0 = *(const short8*)(kr + (((hi) ^ (key & 7)) << 4));
      const short8 ka1 = *(const short8*)(kr + (((hi + 4) ^ (key & 7)) << 4));
      f32x4 z = {};
      z = mfma16x16x32(ka0, bq0, z);
      z = mfma16x16x32(ka1, bq1, z);
      s[nt] = z;      // s[nt][e] = S[q=lr][key = nt*16 + hi*4 + e]
    }
    __builtin_amdgcn_s_setprio(0);
    // bias + mask + softmax (per-lane row; reduce over {lr, lr+16, lr+32, lr+48})
    float mx = -3.0e38f;
    #pragma unroll
    for (int nt = 0; nt < 13; ++nt) {
      #pragma unroll
      for (int e = 0; e < 4; ++e) {
        const int key = nt * 16 + hi * 4 + e;
        const int kh = key / 14, kw = key - kh * 14;
        float v = s[nt][e] * 0.125f + __bfloat162float(relh_s[qc * 14 + kh])
                                    + __bfloat162float(relw_s[qc * 14 + kw]);
        v = (key < 196) ? v : -3.0e38f;
        s[nt][e] = v;
        mx = fmaxf(mx, v);
      }
    }
    mx = fmaxf(mx, __shfl_xor(mx, 16));
    mx = fmaxf(mx, __shfl_xor(mx, 32));
    float sm = 0.f;
    #pragma unroll
    for (int nt = 0; nt < 13; ++nt)
      #pragma unroll
      for (int e = 0; e < 4; ++e) {
        const float p = __expf(s[nt][e] - mx);
        s[nt][e] = p; sm += p;
      }
    sm += __shfl_xor(sm, 16);
    sm += __shfl_xor(sm, 32);
    const float rinv = 1.f / sm;
    s[13] = f32x4{0.f, 0.f, 0.f, 0.f};   // keys 208..223: P = 0 exactly
    // O^T = V^T . P^T  (7 key chunks of 32); P frag built in-register
    f32x4 o[4] = {};
    #pragma unroll
    for (int kk = 0; kk < 7; ++kk) {
      const uint32_t x0 = cvtpk(s[2 * kk][0] * rinv, s[2 * kk][1] * rinv);
      const uint32_t x1 = cvtpk(s[2 * kk][2] * rinv, s[2 * kk][3] * rinv);
      const uint32_t y0 = cvtpk(s[2 * kk + 1][0] * rinv, s[2 * kk + 1][1] * rinv);
      const uint32_t y1 = cvtpk(s[2 * kk + 1][2] * rinv, s[2 * kk + 1][3] * rinv);
      const uint32_t s0 = (hi < 2) ? y0 : x0, s1 = (hi < 2) ? y1 : x1;
      const uint32_t t0 = __shfl_xor(s0, 32), t1 = __shfl_xor(s1, 32);
      const uint32_t o0 = (hi < 2) ? x0 : y0, o1 = (hi < 2) ? x1 : y1;
      const bool sendOwn = (hi == 1) || (hi == 2);
      const uint32_t u0 = sendOwn ? o0 : t0, u1 = sendOwn ? o1 : t1;
      const uint32_t r0 = __shfl_xor(u0, 16), r1 = __shfl_xor(u1, 16);
      union { uint32_t u[4]; short8 v; } pf;
      pf.u[0] = (hi == 0) ? x0 : ((hi == 2) ? t0 : r0);
      pf.u[1] = (hi == 0) ? x1 : ((hi == 2) ? t1 : r1);
      pf.u[2] = (hi == 3) ? y0 : ((hi == 1) ? t0 : r0);
      pf.u[3] = (hi == 3) ? y1 : ((hi == 1) ? t1 : r1);
      __builtin_amdgcn_s_setprio(1);
      #pragma unroll
      for (int n2 = 0; n2 < 4; ++n2) {
        const int d = n2 * 16 + lr;
        const int idx = d * 448 + (kk * 32 + hi * 8) * 2;
        const short8 va = *(const short8*)(vtb + (idx ^ ((lr & 7) << 4)));
        o[n2] = mfma16x16x32(va, pf.v, o[n2]);   // o[n2][e] = O[q][d=n2*16+hi*4+e]
      }
      __builtin_amdgcn_s_setprio(0);
    }
    // store O rows (dense 8B per lane, aout[head][MPAD][64])
    if (q < 196) {
      bf16* orow = aout + ((size_t)head * MPAD + win * 196 + q) * 64;
      #pragma unroll
      for (int n2 = 0; n2 < 4; ++n2) {
        uint32_t d0 = cvtpk(o[n2][0], o[n2][1]);
        uint32_t d1 = cvtpk(o[n2][2], o[n2][3]);
        uint32_t* dst = (uint32_t*)&orow[n2 * 16 + hi * 4];
        dst[0] = d0; dst[1] = d1;
      }
    }
  }
}

// ---------------- host ----------------
extern "C" void kernel_launch(void* const* d_in, const int* in_sizes, int n_in,
                              void* d_out, int out_size, void* d_ws, size_t ws_size,
                              hipStream_t stream) {
  (void)in_sizes; (void)n_in; (void)out_size; (void)ws_size;
  const float* x      = (const float*)d_in[0];
  const float* ln1_g  = (const float*)d_in[1];
  const float* ln1_b  = (const float*)d_in[2];
  const float* qkv_w  = (const float*)d_in[3];
  const float* qkv_b  = (const float*)d_in[4];
  const float* proj_w = (const float*)d_in[5];
  const float* proj_b = (const float*)d_in[6];
  const float* rph    = (const float*)d_in[7];
  const float* rpw    = (const float*)d_in[8];
  const float* ln2_g  = (const float*)d_in[9];
  const float* ln2_b  = (const float*)d_in[10];
  const float* w1     = (const float*)d_in[11];
  const float* b1v    = (const float*)d_in[12];
  const float* w2     = (const float*)d_in[13];
  const float* b2v    = (const float*)d_in[14];
  float* outp = (float*)d_out;   // also serves as x1 (written by proj epilogue)

  char* ws = (char*)d_ws;
  size_t off = 0;
  auto alloc = [&](size_t bytes) { char* p = ws + off; off += (bytes + 255) & ~(size_t)255; return p; };
  bf16* qkv_wt  = (bf16*)alloc((size_t)2304 * 768 * 2);
  bf16* proj_wt = (bf16*)alloc((size_t)768 * 768 * 2);
  bf16* w1t     = (bf16*)alloc((size_t)3072 * 768 * 2);
  bf16* w2t     = (bf16*)alloc((size_t)768 * 3072 * 2);
  const size_t szB1 = (size_t)MPAD * 768 * 2;
  const size_t szB2 = (size_t)TOK2 * 768 * 2;
  char* regB = alloc(szB1 > szB2 ? szB1 : szB2);
  const size_t szQKV = (size_t)3 * 12 * MPAD * 64 * 2;
  const size_t szH   = (size_t)TOK2 * 3072 * 2;
  char* regC = alloc(szQKV > szH ? szQKV : szH);

  bf16* xnwin   = (bf16*)regB;
  bf16* attnout = (bf16*)regB;
  bf16* xn2     = (bf16*)regB;
  bf16* qbuf    = (bf16*)regC;                       // [12][MPAD][64]
  bf16* kbuf    = qbuf + (size_t)12 * MPAD * 64;
  bf16* vbuf    = kbuf + (size_t)12 * MPAD * 64;
  bf16* hbuf    = (bf16*)regC;

  transpose_cast<<<dim3(2304 / 32, 768 / 32), 256, 0, stream>>>(qkv_w, qkv_wt, 768, 2304);
  transpose_cast<<<dim3(768 / 32, 768 / 32), 256, 0, stream>>>(proj_w, proj_wt, 768, 768);
  transpose_cast<<<dim3(3072 / 32, 768 / 32), 256, 0, stream>>>(w1, w1t, 768, 3072);
  transpose_cast<<<dim3(768 / 32, 3072 / 32), 256, 0, stream>>>(w2, w2t, 3072, 768);

  ln1_partition<<<dim3(MROWS / 4), 256, 0, stream>>>(x, ln1_g, ln1_b, xnwin);

  gemm_bf16<0><<<dim3(2304 / 128, MPAD / 128), 256, 0, stream>>>(
      xnwin, qkv_wt, qkv_b, 768, MROWS, nullptr, nullptr, qbuf, kbuf, vbuf);

  attn_kernel<<<dim3(2400), 512, 0, stream>>>(qbuf, kbuf, vbuf, rph, rpw, attnout);

  gemm_bf16<1><<<dim3(768 / 128, MPAD / 128), 256, 0, stream>>>(
      attnout, proj_wt, proj_b, 768, MROWS, x, outp, nullptr, nullptr, nullptr);

  ln2_kernel<<<dim3(TOK2 / 4), 256, 0, stream>>>(outp, ln2_g, ln2_b, xn2);

  gemm_bf16<2><<<dim3(3072 / 128, TOK2 / 128), 256, 0, stream>>>(
      xn2, w1t, b1v, 768, TOK2, nullptr, nullptr, hbuf, nullptr, nullptr);
  gemm_bf16<3><<<dim3(768 / 128, TOK2 / 128), 256, 0, stream>>>(
      hbuf, w2t, b2v, 3072, TOK2, outp, outp, nullptr, nullptr, nullptr);
}

// Round 12
// 1102.955 us; speedup vs baseline: 1.2166x; 1.1839x over previous
//
#include <hip/hip_runtime.h>
#include <hip/hip_bf16.h>
#include <cstdint>
#include <cstddef>

using bf16 = __hip_bfloat16;
typedef __attribute__((ext_vector_type(8))) short short8;
typedef __attribute__((ext_vector_type(4))) float f32x4;

typedef __attribute__((address_space(1))) const void as1_void;
typedef __attribute__((address_space(3))) void as3_void;

__device__ __forceinline__ f32x4 mfma16x16x32(short8 a, short8 b, f32x4 c) {
  return __builtin_amdgcn_mfma_f32_16x16x32_bf16(a, b, c, 0, 0, 0);
}

__device__ __forceinline__ void gload_lds16(const void* g, void* l) {
  __builtin_amdgcn_global_load_lds((as1_void*)g, (as3_void*)l, 16, 0, 0);
}

__device__ __forceinline__ uint32_t cvtpk(float a, float b) {
  uint32_t r;
  asm("v_cvt_pk_bf16_f32 %0, %1, %2" : "=v"(r) : "v"(a), "v"(b));
  return r;
}

__device__ __forceinline__ float gelu_f(float v) {
  const float u = 0.7978845608f * v * (1.f + 0.044715f * v * v);
  const float e = __expf(-2.f * fabsf(u));
  const float t = (1.f - e) / (1.f + e);
  return 0.5f * v * (1.f + (u < 0.f ? -t : t));
}

// ---------------- problem constants ----------------
static constexpr int MROWS = 39200;
static constexpr int MPAD  = 39296;
static constexpr int TOK2  = 32768;

// ---------------- weight transpose+cast:  in f32 [K][N] -> out bf16 [N][K] ----
__global__ __launch_bounds__(256)
void transpose_cast(const float* __restrict__ in, bf16* __restrict__ out, int K, int N) {
  __shared__ float t[32][33];
  const int tx = threadIdx.x & 31, ty = threadIdx.x >> 5;
  const int bx = blockIdx.x, by = blockIdx.y;
  const int x = bx * 32 + tx;
  for (int r = ty; r < 32; r += 8)
    t[r][tx] = in[(size_t)(by * 32 + r) * N + x];
  __syncthreads();
  const int xo = by * 32 + tx;
  for (int r = ty; r < 32; r += 8)
    out[(size_t)(bx * 32 + r) * K + xo] = __float2bfloat16(t[tx][r]);
}

// ---------------- LN1 + window partition -> bf16 [MPAD][768] ----------------
__global__ __launch_bounds__(256)
void ln1_partition(const float* __restrict__ x, const float* __restrict__ g,
                   const float* __restrict__ bb, bf16* __restrict__ out) {
  const int token = blockIdx.x * 4 + (threadIdx.x >> 6);
  const int lane = threadIdx.x & 63;
  const int win = token / 196, tok = token % 196;
  const int b_ = win / 25, wh = (win / 5) % 5, ww = win % 5;
  const int i = tok / 14, j = tok % 14;
  const int h = wh * 14 + i, w = ww * 14 + j;
  bf16* o = out + (size_t)token * 768;
  if (h >= 64 || w >= 64) {
    for (int t = 0; t < 12; ++t) o[lane + 64 * t] = __float2bfloat16(0.f);
    return;
  }
  const float* src = x + ((size_t)((b_ * 64 + h) * 64 + w)) * 768;
  float vals[12], s = 0.f, ss = 0.f;
  #pragma unroll
  for (int t = 0; t < 12; ++t) {
    float v = src[lane + 64 * t];
    vals[t] = v; s += v; ss += v * v;
  }
  #pragma unroll
  for (int d = 32; d > 0; d >>= 1) { s += __shfl_xor(s, d); ss += __shfl_xor(ss, d); }
  const float mu = s * (1.f / 768.f);
  const float var = ss * (1.f / 768.f) - mu * mu;
  const float inv = rsqrtf(var + 1e-6f);
  #pragma unroll
  for (int t = 0; t < 12; ++t) {
    const int c = lane + 64 * t;
    o[c] = __float2bfloat16((vals[t] - mu) * inv * g[c] + bb[c]);
  }
}

// ---------------- LN2 on x1 (f32, dense [32768][768]) -> bf16 ----------------
__global__ __launch_bounds__(256)
void ln2_kernel(const float* __restrict__ x1, const float* __restrict__ g,
                const float* __restrict__ bb, bf16* __restrict__ out) {
  const int token = blockIdx.x * 4 + (threadIdx.x >> 6);
  const int lane = threadIdx.x & 63;
  const float* src = x1 + (size_t)token * 768;
  bf16* o = out + (size_t)token * 768;
  float vals[12], s = 0.f, ss = 0.f;
  #pragma unroll
  for (int t = 0; t < 12; ++t) {
    float v = src[lane + 64 * t];
    vals[t] = v; s += v; ss += v * v;
  }
  #pragma unroll
  for (int d = 32; d > 0; d >>= 1) { s += __shfl_xor(s, d); ss += __shfl_xor(ss, d); }
  const float mu = s * (1.f / 768.f);
  const float var = ss * (1.f / 768.f) - mu * mu;
  const float inv = rsqrtf(var + 1e-6f);
  #pragma unroll
  for (int t = 0; t < 12; ++t) {
    const int c = lane + 64 * t;
    o[c] = __float2bfloat16((vals[t] - mu) * inv * g[c] + bb[c]);
  }
}

// ---------------- generic bf16 GEMM, 128x128 tile, BK=32, 2-phase dbuf ------
// (r5/r6-proven structure; counted-vmcnt confirmed null at 2-phase)
// EPI 0: qkv -> q/k/v [head][MPAD][64] (LDS-staged stores)
// EPI 1: proj (A in [head][MPAD][64]) + unpartition + residual (f32)
// EPI 2: gelu -> bf16 [M][3072] (LDS-staged stores)
// EPI 3: dense residual add (f32)
template<int EPI>
__global__ __launch_bounds__(256)
void gemm_bf16(const bf16* __restrict__ A, const bf16* __restrict__ Bt,
               const float* __restrict__ bias, int K, int Mreal,
               const float* __restrict__ fin, float* __restrict__ fout,
               bf16* __restrict__ ob0, bf16* __restrict__ ob1, bf16* __restrict__ ob2) {
  __shared__ __align__(16) bf16 SMEM[16384];                 // 32 KB
  bf16* const lA0 = SMEM;
  bf16* const lA1 = SMEM + 4096;
  bf16* const lB0 = SMEM + 8192;
  bf16* const lB1 = SMEM + 12288;
  const int tid = threadIdx.x;
  const int lane = tid & 63, wv = tid >> 6;
  const int lr = lane & 15, hi = lane >> 4;
  const int wm = wv >> 1, wn = wv & 1;

  // bijective chunked XCD swizzle (m204)
  const int gx = gridDim.x;
  const int nwg = gx * gridDim.y;
  int lin = blockIdx.y * gx + blockIdx.x;
  {
    const int q8 = nwg >> 3, r8 = nwg & 7;
    const int xcd = lin & 7, pos = lin >> 3;
    lin = (xcd < r8 ? xcd * (q8 + 1) : r8 * (q8 + 1) + (xcd - r8) * q8) + pos;
  }
  const size_t arow0 = (size_t)(lin / gx) * 128;
  const size_t brow0 = (size_t)(lin % gx) * 128;
  f32x4 acc[4][4] = {};

  auto stage = [&](bf16* bufA, bf16* bufB, int kt) {
    const int k0 = kt * 32;
    #pragma unroll
    for (int it = 0; it < 2; ++it) {
      const int seg = it * 256 + tid;
      const int row = seg >> 2, kq = seg & 3;
      const size_t dst = (size_t)(it * 256 + wv * 64) * 8;
      if constexpr (EPI == 1) {
        const int k = k0 + kq * 8;   // A layout: [head][MPAD][64]
        gload_lds16(A + ((size_t)(k >> 6) * MPAD + arow0 + row) * 64 + (k & 63), bufA + dst);
      } else {
        gload_lds16(A + (arow0 + row) * K + k0 + kq * 8, bufA + dst);
      }
      gload_lds16(Bt + (brow0 + row) * K + k0 + kq * 8, bufB + dst);
    }
  };
  auto compute = [&](const bf16* bufA, const bf16* bufB) {
    short8 af[4], bfr[4];
    #pragma unroll
    for (int m = 0; m < 4; ++m) af[m] = *(const short8*)&bufA[(wm * 64 + m * 16 + lr) * 32 + hi * 8];
    #pragma unroll
    for (int n = 0; n < 4; ++n) bfr[n] = *(const short8*)&bufB[(wn * 64 + n * 16 + lr) * 32 + hi * 8];
    #pragma unroll
    for (int m = 0; m < 4; ++m)
      #pragma unroll
      for (int n = 0; n < 4; ++n)
        acc[m][n] = mfma16x16x32(af[m], bfr[n], acc[m][n]);
  };

  const int nt = K >> 5;               // even (24 or 96)
  stage(lA0, lB0, 0);
  __syncthreads();
  for (int t = 0; t < nt; t += 2) {
    if (t + 1 < nt) stage(lA1, lB1, t + 1);
    compute(lA0, lB0);
    __syncthreads();
    if (t + 2 < nt) stage(lA0, lB0, t + 2);
    compute(lA1, lB1);
    __syncthreads();
  }

  if constexpr (EPI == 0 || EPI == 2) {
    // ---- LDS-staged coalesced bf16 epilogue ----
    bf16* ct = SMEM;                   // 128x128 bf16 tile, XOR-swizzled rows
    #pragma unroll
    for (int n = 0; n < 4; ++n) {
      const int col = wn * 64 + n * 16 + lr;         // tile-local
      const float bv = bias[(int)brow0 + col];
      #pragma unroll
      for (int m = 0; m < 4; ++m) {
        #pragma unroll
        for (int e = 0; e < 4; ++e) {
          const int row = wm * 64 + m * 16 + hi * 4 + e;
          float v = acc[m][n][e] + bv;
          if constexpr (EPI == 2) v = gelu_f(v);
          const int byte = (row << 8) + (col << 1);
          *(bf16*)((char*)ct + (byte ^ ((row & 7) << 5))) = __float2bfloat16(v);
        }
      }
    }
    __syncthreads();
    #pragma unroll
    for (int i = 0; i < 8; ++i) {
      const int lin16 = i * 256 + tid;           // 16-B unit index
      const int row = lin16 >> 4;
      const int u   = lin16 & 15;
      const int byte = (row << 8) + (u << 4);
      const short8 val = *(const short8*)((char*)ct + (byte ^ ((row & 7) << 5)));
      const int grow = (int)arow0 + row;
      const int gcol = (int)brow0 + u * 8;
      if constexpr (EPI == 0) {
        if (grow < Mreal) {
          const int which = gcol / 768, head = (gcol >> 6) % 12, d = gcol & 63;
          bf16* dstb = (which == 0) ? ob0 : ((which == 1) ? ob1 : ob2);
          *(short8*)&dstb[((size_t)head * MPAD + grow) * 64 + d] = val;
        }
      } else {
        *(short8*)&ob0[(size_t)grow * 3072 + gcol] = val;
      }
    }
  } else {
    // ---- f32 residual epilogues (direct) ----
    #pragma unroll
    for (int n = 0; n < 4; ++n) {
      const int col = (int)brow0 + wn * 64 + n * 16 + lr;
      const float bv = bias[col];
      #pragma unroll
      for (int m = 0; m < 4; ++m) {
        #pragma unroll
        for (int e = 0; e < 4; ++e) {
          const int row = (int)arow0 + wm * 64 + m * 16 + hi * 4 + e;
          const float v = acc[m][n][e] + bv;
          if constexpr (EPI == 1) {
            if (row < Mreal) {
              const int win = row / 196, tok = row % 196;
              const int b_ = win / 25, wh = (win / 5) % 5, ww = win % 5;
              const int i = tok / 14, j = tok % 14;
              const int h = wh * 14 + i, w = ww * 14 + j;
              if (h < 64 && w < 64) {
                const size_t idx = ((size_t)((b_ * 64 + h) * 64 + w)) * 768 + col;
                fout[idx] = fin[idx] + v;
              }
            }
          } else {
            const size_t idx = (size_t)row * 768 + col;
            fout[idx] = fin[idx] + v;
          }
        }
      }
    }
  }
}

// ---------------- fused window attention, one block per (window, head) -------
// 512 threads (8 waves), 65 KB LDS. launch_bounds(512,2): VGPR cap 256 so the
// compiler CANNOT spill (r11's (512,4) rounded VGPR down to 64 -> 692 MB of
// scratch writes). P is early-packed to bf16 (pk0/pk1, 28 u32) right after
// exp+sum, and rinv is applied once to O -> peak live regs ~90-100, giving a
// shot at 2 blocks/CU (16 waves) with zero spill risk.
__global__ __launch_bounds__(512, 2)
void attn_kernel(const bf16* __restrict__ qb, const bf16* __restrict__ kb,
                 const bf16* __restrict__ vb, const float* __restrict__ rph,
                 const float* __restrict__ rpw, bf16* __restrict__ aout) {
  __shared__ __align__(16) char SM[65248];
  bf16* pbh    = (bf16*)SM;
  bf16* pbw    = (bf16*)(SM + 4096);
  bf16* Gh     = (bf16*)(SM + 8192);
  bf16* Gw     = (bf16*)(SM + 23168);
  char* klds   = SM;                    // [200 rows][128 B], XOR-swizzled
  char* vtb    = SM + 25600;            // [64 d][448 B], XOR-swizzled
  bf16* relh_s = (bf16*)(SM + 54272);   // [196][14]
  bf16* relw_s = (bf16*)(SM + 59760);   // [196][14]

  const int bh = blockIdx.x;             // 0..2399
  const int win = bh / 12, head = bh % 12;
  const size_t base = ((size_t)head * MPAD + win * 196) * 64;
  const bf16* Q  = qb + base;
  const bf16* Kp = kb + base;
  const bf16* Vp = vb + base;
  const int tid = threadIdx.x, lane = tid & 63, wv = tid >> 6;   // wv 0..7
  const int lr = lane & 15, hi = lane >> 4;

  // ---- stage rel_pos (bf16, zero-padded to 32 rows) ----
  for (int i = tid; i < 32 * 64; i += 512) {
    const int r = i >> 6, c = i & 63;
    const bool ok = r < 27;
    pbh[i] = __float2bfloat16(ok ? rph[r * 64 + c] : 0.f);
    pbw[i] = __float2bfloat16(ok ? rpw[r * 64 + c] : 0.f);
  }
  __syncthreads();
  // ---- phase A: G = Q @ relpos^T via MFMA ----
  {
    short8 bh00 = *(const short8*)&pbh[(lr) * 64 + hi * 8];
    short8 bh01 = *(const short8*)&pbh[(lr) * 64 + 32 + hi * 8];
    short8 bh10 = *(const short8*)&pbh[(16 + lr) * 64 + hi * 8];
    short8 bh11 = *(const short8*)&pbh[(16 + lr) * 64 + 32 + hi * 8];
    short8 bw00 = *(const short8*)&pbw[(lr) * 64 + hi * 8];
    short8 bw01 = *(const short8*)&pbw[(lr) * 64 + 32 + hi * 8];
    short8 bw10 = *(const short8*)&pbw[(16 + lr) * 64 + hi * 8];
    short8 bw11 = *(const short8*)&pbw[(16 + lr) * 64 + 32 + hi * 8];
    for (int mt = wv; mt < 13; mt += 8) {
      const short8 a0 = *(const short8*)&Q[(mt * 16 + lr) * 64 + hi * 8];
      const short8 a1 = *(const short8*)&Q[(mt * 16 + lr) * 64 + 32 + hi * 8];
      f32x4 g0 = {}, g1 = {}, g2 = {}, g3 = {};
      g0 = mfma16x16x32(a0, bh00, g0); g0 = mfma16x16x32(a1, bh01, g0);
      g1 = mfma16x16x32(a0, bh10, g1); g1 = mfma16x16x32(a1, bh11, g1);
      g2 = mfma16x16x32(a0, bw00, g2); g2 = mfma16x16x32(a1, bw01, g2);
      g3 = mfma16x16x32(a0, bw10, g3); g3 = mfma16x16x32(a1, bw11, g3);
      #pragma unroll
      for (int e = 0; e < 4; ++e) {
        const int row = mt * 16 + hi * 4 + e;
        Gh[row * 36 + lr]      = __float2bfloat16(g0[e]);
        Gh[row * 36 + 16 + lr] = __float2bfloat16(g1[e]);
        Gw[row * 36 + lr]      = __float2bfloat16(g2[e]);
        Gw[row * 36 + 16 + lr] = __float2bfloat16(g3[e]);
      }
    }
  }
  __syncthreads();
  // ---- gather G -> regs ----
  bf16 ghr[6], gwr[6];
  #pragma unroll
  for (int t = 0; t < 6; ++t) {
    const int i = tid + t * 512;
    if (i < 196 * 14) {
      const int q = i / 14, kk = i - (i / 14) * 14;
      const int rh = q / 14 - kk + 13;
      const int rw2 = q - (q / 14) * 14 - kk + 13;
      ghr[t] = Gh[q * 36 + rh];
      gwr[t] = Gw[q * 36 + rw2];
    }
  }
  __syncthreads();
  // ---- write rel tables; stage K (swizzled gload_lds); stage V^T ----
  #pragma unroll
  for (int t = 0; t < 6; ++t) {
    const int i = tid + t * 512;
    if (i < 196 * 14) { relh_s[i] = ghr[t]; relw_s[i] = gwr[t]; }
  }
  for (int c = wv; c < 25; c += 8) {          // 25 chunks x 1024 B = 200 K-rows
    const int row = c * 8 + (lane >> 3);
    const int ch  = (lane & 7) ^ (row & 7);   // pre-swizzled global source
    gload_lds16(Kp + row * 64 + ch * 8, klds + c * 1024);
  }
  for (int i = tid; i < 196 * 8; i += 512) {  // V^T staging (vectorized read)
    const int key = i >> 3, dg = (i & 7) * 8;
    const short8 v = *(const short8*)&Vp[key * 64 + dg];
    #pragma unroll
    for (int j = 0; j < 8; ++j) {
      const int idx = (dg + j) * 448 + key * 2;
      *(bf16*)(vtb + (idx ^ (j << 4))) = ((const bf16*)&v)[j];
    }
  }
  for (int i = tid; i < 64 * 28; i += 512) {  // zero-pad keys 196..223
    const int d = i / 28, key = 196 + i - (i / 28) * 28;
    const int idx = d * 448 + key * 2;
    *(bf16*)(vtb + (idx ^ ((d & 7) << 4))) = __float2bfloat16(0.f);
  }
  __syncthreads();

  // ---- main loop over q-tiles (8 waves cover 13 tiles) ----
  for (int qt = wv; qt < 13; qt += 8) {
    const int q = qt * 16 + lr;               // this lane's q-row
    const int qc = q < 196 ? q : 195;
    const short8 bq0 = *(const short8*)&Q[(qt * 16 + lr) * 64 + hi * 8];
    const short8 bq1 = *(const short8*)&Q[(qt * 16 + lr) * 64 + 32 + hi * 8];
    // S^T = K . Q^T  (13 key tiles of 16)
    f32x4 s[13];
    __builtin_amdgcn_s_setprio(1);
    #pragma unroll
    for (int nt = 0; nt < 13; ++nt) {
      const int key = nt * 16 + lr;
      const char* kr = klds + key * 128;
      const short8 ka0 = *(const short8*)(kr + (((hi) ^ (key & 7)) << 4));
      const short8 ka1 = *(const short8*)(kr + (((hi + 4) ^ (key & 7)) << 4));
      f32x4 z = {};
      z = mfma16x16x32(ka0, bq0, z);
      z = mfma16x16x32(ka1, bq1, z);
      s[nt] = z;      // s[nt][e] = S[q=lr][key = nt*16 + hi*4 + e]
    }
    __builtin_amdgcn_s_setprio(0);
    // bias + mask + softmax max (per-lane row; reduce over {lr,lr+16,lr+32,lr+48})
    float mx = -3.0e38f;
    #pragma unroll
    for (int nt = 0; nt < 13; ++nt) {
      #pragma unroll
      for (int e = 0; e < 4; ++e) {
        const int key = nt * 16 + hi * 4 + e;
        const int kh = key / 14, kw = key - kh * 14;
        float v = s[nt][e] * 0.125f + __bfloat162float(relh_s[qc * 14 + kh])
                                    + __bfloat162float(relw_s[qc * 14 + kw]);
        v = (key < 196) ? v : -3.0e38f;
        s[nt][e] = v;
        mx = fmaxf(mx, v);
      }
    }
    mx = fmaxf(mx, __shfl_xor(mx, 16));
    mx = fmaxf(mx, __shfl_xor(mx, 32));
    // exp + sum + EARLY PACK to bf16 (halves live state; rinv applied to O)
    float sm = 0.f;
    uint32_t pk0[14], pk1[14];
    #pragma unroll
    for (int nt = 0; nt < 13; ++nt) {
      const float p0 = __expf(s[nt][0] - mx);
      const float p1 = __expf(s[nt][1] - mx);
      const float p2 = __expf(s[nt][2] - mx);
      const float p3 = __expf(s[nt][3] - mx);
      sm += (p0 + p1) + (p2 + p3);
      pk0[nt] = cvtpk(p0, p1);
      pk1[nt] = cvtpk(p2, p3);
    }
    pk0[13] = 0u; pk1[13] = 0u;          // keys 208..223: P = 0 exactly
    sm += __shfl_xor(sm, 16);
    sm += __shfl_xor(sm, 32);
    const float rinv = 1.f / sm;
    // O^T = V^T . P^T  (7 key chunks of 32); P frag exchanged in-register
    f32x4 o[4] = {};
    #pragma unroll
    for (int kk = 0; kk < 7; ++kk) {
      const uint32_t x0 = pk0[2 * kk],     x1 = pk1[2 * kk];
      const uint32_t y0 = pk0[2 * kk + 1], y1 = pk1[2 * kk + 1];
      const uint32_t s0 = (hi < 2) ? y0 : x0, s1 = (hi < 2) ? y1 : x1;
      const uint32_t t0 = __shfl_xor(s0, 32), t1 = __shfl_xor(s1, 32);
      const uint32_t o0 = (hi < 2) ? x0 : y0, o1 = (hi < 2) ? x1 : y1;
      const bool sendOwn = (hi == 1) || (hi == 2);
      const uint32_t u0 = sendOwn ? o0 : t0, u1 = sendOwn ? o1 : t1;
      const uint32_t r0 = __shfl_xor(u0, 16), r1 = __shfl_xor(u1, 16);
      union { uint32_t u[4]; short8 v; } pf;
      pf.u[0] = (hi == 0) ? x0 : ((hi == 2) ? t0 : r0);
      pf.u[1] = (hi == 0) ? x1 : ((hi == 2) ? t1 : r1);
      pf.u[2] = (hi == 3) ? y0 : ((hi == 1) ? t0 : r0);
      pf.u[3] = (hi == 3) ? y1 : ((hi == 1) ? t1 : r1);
      __builtin_amdgcn_s_setprio(1);
      #pragma unroll
      for (int n2 = 0; n2 < 4; ++n2) {
        const int d = n2 * 16 + lr;
        const int idx = d * 448 + (kk * 32 + hi * 8) * 2;
        const short8 va = *(const short8*)(vtb + (idx ^ ((lr & 7) << 4)));
        o[n2] = mfma16x16x32(va, pf.v, o[n2]);   // o[n2][e] = O[q][d=n2*16+hi*4+e]
      }
      __builtin_amdgcn_s_setprio(0);
    }
    // scale by rinv + store O rows (dense 8B per lane, aout[head][MPAD][64])
    if (q < 196) {
      bf16* orow = aout + ((size_t)head * MPAD + win * 196 + q) * 64;
      #pragma unroll
      for (int n2 = 0; n2 < 4; ++n2) {
        uint32_t d0 = cvtpk(o[n2][0] * rinv, o[n2][1] * rinv);
        uint32_t d1 = cvtpk(o[n2][2] * rinv, o[n2][3] * rinv);
        uint32_t* dst = (uint32_t*)&orow[n2 * 16 + hi * 4];
        dst[0] = d0; dst[1] = d1;
      }
    }
  }
}

// ---------------- host ----------------
extern "C" void kernel_launch(void* const* d_in, const int* in_sizes, int n_in,
                              void* d_out, int out_size, void* d_ws, size_t ws_size,
                              hipStream_t stream) {
  (void)in_sizes; (void)n_in; (void)out_size; (void)ws_size;
  const float* x      = (const float*)d_in[0];
  const float* ln1_g  = (const float*)d_in[1];
  const float* ln1_b  = (const float*)d_in[2];
  const float* qkv_w  = (const float*)d_in[3];
  const float* qkv_b  = (const float*)d_in[4];
  const float* proj_w = (const float*)d_in[5];
  const float* proj_b = (const float*)d_in[6];
  const float* rph    = (const float*)d_in[7];
  const float* rpw    = (const float*)d_in[8];
  const float* ln2_g  = (const float*)d_in[9];
  const float* ln2_b  = (const float*)d_in[10];
  const float* w1     = (const float*)d_in[11];
  const float* b1v    = (const float*)d_in[12];
  const float* w2     = (const float*)d_in[13];
  const float* b2v    = (const float*)d_in[14];
  float* outp = (float*)d_out;   // also serves as x1 (written by proj epilogue)

  char* ws = (char*)d_ws;
  size_t off = 0;
  auto alloc = [&](size_t bytes) { char* p = ws + off; off += (bytes + 255) & ~(size_t)255; return p; };
  bf16* qkv_wt  = (bf16*)alloc((size_t)2304 * 768 * 2);
  bf16* proj_wt = (bf16*)alloc((size_t)768 * 768 * 2);
  bf16* w1t     = (bf16*)alloc((size_t)3072 * 768 * 2);
  bf16* w2t     = (bf16*)alloc((size_t)768 * 3072 * 2);
  const size_t szB1 = (size_t)MPAD * 768 * 2;
  const size_t szB2 = (size_t)TOK2 * 768 * 2;
  char* regB = alloc(szB1 > szB2 ? szB1 : szB2);
  const size_t szQKV = (size_t)3 * 12 * MPAD * 64 * 2;
  const size_t szH   = (size_t)TOK2 * 3072 * 2;
  char* regC = alloc(szQKV > szH ? szQKV : szH);

  bf16* xnwin   = (bf16*)regB;
  bf16* attnout = (bf16*)regB;
  bf16* xn2     = (bf16*)regB;
  bf16* qbuf    = (bf16*)regC;                       // [12][MPAD][64]
  bf16* kbuf    = qbuf + (size_t)12 * MPAD * 64;
  bf16* vbuf    = kbuf + (size_t)12 * MPAD * 64;
  bf16* hbuf    = (bf16*)regC;

  transpose_cast<<<dim3(2304 / 32, 768 / 32), 256, 0, stream>>>(qkv_w, qkv_wt, 768, 2304);
  transpose_cast<<<dim3(768 / 32, 768 / 32), 256, 0, stream>>>(proj_w, proj_wt, 768, 768);
  transpose_cast<<<dim3(3072 / 32, 768 / 32), 256, 0, stream>>>(w1, w1t, 768, 3072);
  transpose_cast<<<dim3(768 / 32, 3072 / 32), 256, 0, stream>>>(w2, w2t, 3072, 768);

  ln1_partition<<<dim3(MROWS / 4), 256, 0, stream>>>(x, ln1_g, ln1_b, xnwin);

  gemm_bf16<0><<<dim3(2304 / 128, MPAD / 128), 256, 0, stream>>>(
      xnwin, qkv_wt, qkv_b, 768, MROWS, nullptr, nullptr, qbuf, kbuf, vbuf);

  attn_kernel<<<dim3(2400), 512, 0, stream>>>(qbuf, kbuf, vbuf, rph, rpw, attnout);

  gemm_bf16<1><<<dim3(768 / 128, MPAD / 128), 256, 0, stream>>>(
      attnout, proj_wt, proj_b, 768, MROWS, x, outp, nullptr, nullptr, nullptr);

  ln2_kernel<<<dim3(TOK2 / 4), 256, 0, stream>>>(outp, ln2_g, ln2_b, xn2);

  gemm_bf16<2><<<dim3(3072 / 128, TOK2 / 128), 256, 0, stream>>>(
      xn2, w1t, b1v, 768, TOK2, nullptr, nullptr, hbuf, nullptr, nullptr);
  gemm_bf16<3><<<dim3(768 / 128, TOK2 / 128), 256, 0, stream>>>(
      hbuf, w2t, b2v, 3072, TOK2, outp, outp, nullptr, nullptr, nullptr);
}